// Round 10
// baseline (87.999 us; speedup 1.0000x reference)
//
#include <hip/hip_runtime.h>
#include <math.h>

#define B_ 8
#define N_ 128
#define M_ 256
#define F_ 256

#define LOG2E2 2.8853900817779268f  // 2*log2(e)

// ---------------------------------------------------------------------------
// K2F: fused u-recompute + bilinear-tanh reduction partials.
// Grid (mg 0..3, ns 0..15, b 0..7) = 512 blocks (2/CU), 512 threads (8 waves).
// NO __launch_bounds__ (round-8 lesson: the min-waves arg clamped VGPR to 32
// -> scratch spill -> 82 us; round-9 unclamped k2 ran clean).
//
// Block owns n rows n0=ns*8..+7, m cols m0=mg*64..+63, all 256 f.
//   wave w = f-chunk fc (32 f);  lane = m offset within mg's 64 m.
//
// Staging order: (1) issue per-thread y-chunk + Ww-chunk loads (in flight
// during A1); (2) A1 recomputes u rows:
//   us[r][g] = (x[n0+r,:].Uw[g,:] + Ub[g])*2log2e   (g = tid&255, 4 rows per
//   thread-half; x rows block-uniform -> s_load, Uw per-lane coalesced).
// A2 hot loop (LDS broadcast + registers only):
//   S[n][m] = sum_f Ww[f]*rcp(exp2(us[n][f]*y[m][f])+1)
//   alpha = Wsum - 2S is monotone-DECREASING in S => reduce MIN of S;
//   Wsum and W_b cancel in max/softmax (shift-invariance). EXACT.
// Partials: rminp[b][mg][n] (min over 64 m), cminp[b][ns][m] (min over 8 n).
// ---------------------------------------------------------------------------
__global__ void k2_fused(const float* __restrict__ x,
                         const float* __restrict__ y,
                         const float* __restrict__ Uw,
                         const float* __restrict__ Ub,
                         const float* __restrict__ Ww,
                         float* __restrict__ rminp,
                         float* __restrict__ cminp) {
  __shared__ float us[8][F_];        //  8 KB
  __shared__ float red[8][8][64];    // 16 KB  [n][fc][m-lane]
  __shared__ float sm[8][64];        //  2 KB

  const int tid  = threadIdx.x;
  const int mg   = blockIdx.x;   // 0..3
  const int ns   = blockIdx.y;   // 0..15
  const int b    = blockIdx.z;   // 0..7
  const int n0   = ns * 8;
  const int m0   = mg * 64;
  const int lane = tid & 63;
  const int w    = tid >> 6;
  const int fc   = __builtin_amdgcn_readfirstlane(w);   // 0..7 (32 f each)

  // ---- (1) per-thread y chunk (32 VGPR) + wave-uniform Ww chunk: issue
  //      BEFORE A1 so the VMEM latency hides under A1's FMA stream ----
  float4 yv[8];
  float4 wwv[8];
  {
    const float* yr = y + ((size_t)(b * M_ + m0 + lane)) * F_ + fc * 32;
    const float* wr = Ww + fc * 32;
#pragma unroll
    for (int j = 0; j < 8; ++j) {
      yv[j]  = *(const float4*)&yr[4 * j];
      wwv[j] = *(const float4*)&wr[4 * j];
    }
  }

  // ---- (2) A1: recompute this block's 8 u rows into LDS ----
  {
    const int g  = tid & 255;
    const int rp = (tid >> 8) * 4;   // 0 or 4
    const float* __restrict__ uwr = Uw + (size_t)g * F_;
    const float* __restrict__ xr  = x + (size_t)(b * N_ + n0 + rp) * F_;
    float a0 = 0.f, a1 = 0.f, a2 = 0.f, a3 = 0.f;
#pragma unroll 4
    for (int f = 0; f < F_; f += 4) {
      const float4 wv = *(const float4*)&uwr[f];           // per-lane
      const float4 x0 = *(const float4*)&xr[0 * F_ + f];   // uniform -> s_load
      const float4 x1 = *(const float4*)&xr[1 * F_ + f];
      const float4 x2 = *(const float4*)&xr[2 * F_ + f];
      const float4 x3 = *(const float4*)&xr[3 * F_ + f];
      a0 = fmaf(wv.x, x0.x, a0); a0 = fmaf(wv.y, x0.y, a0);
      a0 = fmaf(wv.z, x0.z, a0); a0 = fmaf(wv.w, x0.w, a0);
      a1 = fmaf(wv.x, x1.x, a1); a1 = fmaf(wv.y, x1.y, a1);
      a1 = fmaf(wv.z, x1.z, a1); a1 = fmaf(wv.w, x1.w, a1);
      a2 = fmaf(wv.x, x2.x, a2); a2 = fmaf(wv.y, x2.y, a2);
      a2 = fmaf(wv.z, x2.z, a2); a2 = fmaf(wv.w, x2.w, a2);
      a3 = fmaf(wv.x, x3.x, a3); a3 = fmaf(wv.y, x3.y, a3);
      a3 = fmaf(wv.z, x3.z, a3); a3 = fmaf(wv.w, x3.w, a3);
    }
    const float ubv = Ub[g];
    us[rp + 0][g] = (a0 + ubv) * LOG2E2;
    us[rp + 1][g] = (a1 + ubv) * LOG2E2;
    us[rp + 2][g] = (a2 + ubv) * LOG2E2;
    us[rp + 3][g] = (a3 + ubv) * LOG2E2;
  }
  __syncthreads();

  // ---- A2 hot loop: LDS broadcast + registers only ----
#define QUAD(nn, j, S0, S1)                                                              \
  do {                                                                                   \
    const float4 uv = *(const float4*)&us[nn][fc * 32 + 4 * (j)];                        \
    S0 = fmaf(wwv[j].x,                                                                  \
              __builtin_amdgcn_rcpf(__builtin_amdgcn_exp2f(uv.x * yv[j].x) + 1.f), S0);  \
    S1 = fmaf(wwv[j].y,                                                                  \
              __builtin_amdgcn_rcpf(__builtin_amdgcn_exp2f(uv.y * yv[j].y) + 1.f), S1);  \
    S0 = fmaf(wwv[j].z,                                                                  \
              __builtin_amdgcn_rcpf(__builtin_amdgcn_exp2f(uv.z * yv[j].z) + 1.f), S0);  \
    S1 = fmaf(wwv[j].w,                                                                  \
              __builtin_amdgcn_rcpf(__builtin_amdgcn_exp2f(uv.w * yv[j].w) + 1.f), S1);  \
  } while (0)

#define DO_N(nn, A)                                                                      \
  do {                                                                                   \
    float s0 = 0.f, s1 = 0.f;                                                            \
    QUAD(nn, 0, s0, s1); QUAD(nn, 1, s0, s1); QUAD(nn, 2, s0, s1); QUAD(nn, 3, s0, s1);  \
    QUAD(nn, 4, s0, s1); QUAD(nn, 5, s0, s1); QUAD(nn, 6, s0, s1); QUAD(nn, 7, s0, s1);  \
    A = s0 + s1;                                                                         \
  } while (0)

  float a0, a1, a2, a3, a4, a5, a6, a7;
  DO_N(0, a0); DO_N(1, a1); DO_N(2, a2); DO_N(3, a3);
  DO_N(4, a4); DO_N(5, a5); DO_N(6, a6); DO_N(7, a7);
#undef DO_N
#undef QUAD

  // ---- cross-fc sum ----
  red[0][fc][lane] = a0; red[1][fc][lane] = a1;
  red[2][fc][lane] = a2; red[3][fc][lane] = a3;
  red[4][fc][lane] = a4; red[5][fc][lane] = a5;
  red[6][fc][lane] = a6; red[7][fc][lane] = a7;
  __syncthreads();

  // wave w finalizes n = w over its 64 m-lanes
  float S = 0.f;
#pragma unroll
  for (int k = 0; k < 8; ++k) S += red[w][k][lane];

  // row-min partial (over this block's 64 m)
  float r = S;
#pragma unroll
  for (int s = 32; s; s >>= 1) r = fminf(r, __shfl_xor(r, s));
  if (lane == 0) rminp[((size_t)b * 4 + mg) * N_ + n0 + w] = r;

  // col-min partial (over this block's 8 n)
  sm[w][lane] = S;
  __syncthreads();
  if (w == 0) {
    float c = sm[0][lane];
#pragma unroll
    for (int k = 1; k < 8; ++k) c = fminf(c, sm[k][lane]);
    cminp[((size_t)b * 16 + ns) * M_ + m0 + lane] = c;
  }
}

// ---------------------------------------------------------------------------
// KB: finish. Grid (b, task): task 0 = x-softmax+x-pool, 1 = y-softmax+y-pool.
// Softmax inputs are -2 * min-partials (exact, shift-invariant).
// ---------------------------------------------------------------------------
__global__ __launch_bounds__(1024) void kb_final(
    const float* __restrict__ x, const float* __restrict__ y,
    const float* __restrict__ rminp, const float* __restrict__ cminp,
    float* __restrict__ out) {
  const int b = blockIdx.x;
  const int task = blockIdx.y;
  const int tid = threadIdx.x;
  const int wv = tid >> 6;
  __shared__ float wgt[M_];
  __shared__ float red[16];
  __shared__ float part[4][256];

  if (task == 0) {
    float rv = -INFINITY;
    if (tid < N_) {
      float v = INFINITY;
#pragma unroll
      for (int mg = 0; mg < 4; ++mg)
        v = fminf(v, rminp[((size_t)b * 4 + mg) * N_ + tid]);
      rv = -2.f * v;
    }
    float m1 = rv;
#pragma unroll
    for (int s = 32; s; s >>= 1) m1 = fmaxf(m1, __shfl_xor(m1, s));
    if ((tid & 63) == 0) red[wv] = m1;
    __syncthreads();
    m1 = red[0];
#pragma unroll
    for (int k = 1; k < 16; ++k) m1 = fmaxf(m1, red[k]);
    __syncthreads();
    const float e1 = (tid < N_) ? __expf(rv - m1) : 0.f;
    float s1 = e1;
#pragma unroll
    for (int s = 32; s; s >>= 1) s1 += __shfl_xor(s1, s);
    if ((tid & 63) == 0) red[wv] = s1;
    __syncthreads();
    s1 = 0.f;
#pragma unroll
    for (int k = 0; k < 16; ++k) s1 += red[k];
    if (tid < N_) wgt[tid] = e1 / s1;
    __syncthreads();

    const int q = tid >> 8, f = tid & 255;
    float accx = 0.f;
#pragma unroll 4
    for (int n = q; n < N_; n += 4)
      accx = fmaf(wgt[n], x[(size_t)(b * N_ + n) * F_ + f], accx);
    part[q][f] = accx;
    __syncthreads();
    if (tid < 256)
      out[b * (2 * F_) + f] = part[0][f] + part[1][f] + part[2][f] + part[3][f];
  } else {
    float cv = -INFINITY;
    if (tid < M_) {
      float c = INFINITY;
#pragma unroll
      for (int ns = 0; ns < 16; ++ns)
        c = fminf(c, cminp[((size_t)b * 16 + ns) * M_ + tid]);
      cv = -2.f * c;
    }
    float m2 = cv;
#pragma unroll
    for (int s = 32; s; s >>= 1) m2 = fmaxf(m2, __shfl_xor(m2, s));
    if ((tid & 63) == 0) red[wv] = m2;
    __syncthreads();
    m2 = red[0];
#pragma unroll
    for (int k = 1; k < 16; ++k) m2 = fmaxf(m2, red[k]);
    __syncthreads();
    const float e2 = (tid < M_) ? __expf(cv - m2) : 0.f;
    float s2 = e2;
#pragma unroll
    for (int s = 32; s; s >>= 1) s2 += __shfl_xor(s2, s);
    if ((tid & 63) == 0) red[wv] = s2;
    __syncthreads();
    s2 = 0.f;
#pragma unroll
    for (int k = 0; k < 16; ++k) s2 += red[k];
    if (tid < M_) wgt[tid] = e2 / s2;
    __syncthreads();

    const int q = tid >> 8, f = tid & 255;
    float accy = 0.f;
#pragma unroll 4
    for (int m = q; m < M_; m += 4)
      accy = fmaf(wgt[m], y[(size_t)(b * M_ + m) * F_ + f], accy);
    part[q][f] = accy;
    __syncthreads();
    if (tid < 256)
      out[b * (2 * F_) + F_ + f] =
          part[0][f] + part[1][f] + part[2][f] + part[3][f];
  }
}

// ---------------------------------------------------------------------------
extern "C" void kernel_launch(void* const* d_in, const int* in_sizes, int n_in,
                              void* d_out, int out_size, void* d_ws, size_t ws_size,
                              hipStream_t stream) {
  (void)in_sizes; (void)n_in; (void)out_size; (void)ws_size;
  const float* x  = (const float*)d_in[0];
  const float* y  = (const float*)d_in[1];
  const float* Uw = (const float*)d_in[2];
  const float* Ub = (const float*)d_in[3];
  const float* Ww = (const float*)d_in[4];
  // d_in[5] (W_b) unused: max/softmax pipeline is shift-invariant.

  float* rminp = (float*)d_ws;              // [B][4][N]    4096 f
  float* cminp = rminp + B_ * 4 * N_;       // [B][16][M]  32768 f
  float* outp  = (float*)d_out;

  k2_fused<<<dim3(4, 16, B_), 512, 0, stream>>>(x, y, Uw, Ub, Ww, rminp, cminp);
  kb_final<<<dim3(B_, 2), 1024, 0, stream>>>(x, y, rminp, cminp, outp);
}

// Round 11
// 82.400 us; speedup vs baseline: 1.0679x; 1.0679x over previous
//
#include <hip/hip_runtime.h>
#include <math.h>

#define B_ 8
#define N_ 128
#define M_ 256
#define F_ 256

#define LOG2E2 2.8853900817779268f  // 2*log2(e)

// ---------------------------------------------------------------------------
// K2F v2: fused u-recompute + bilinear-tanh reduction partials.
// Grid (mg 0..3, ns 0..15, b 0..7) = 512 blocks (2/CU), 512 threads (8 waves).
// NO min-waves launch_bounds arg (round 8: clamped VGPR->32, spill).
// Phase ORDER: A1 compute -> stage y/Ww regs -> sync -> hot loop.
//   (round 10: staging BEFORE A1 kept 64 VGPRs live across A1 -> spill@64.)
//
// Block owns n rows n0=ns*8..+7, m cols m0=mg*64..+63, all 256 f.
//   wave w = f-chunk fc (32 f);  lane = m offset within mg's 64 m.
//
// A1: us[r][g] = (x[n0+r,:].Uw[g,:] + Ub[g])*2log2e  (g = tid&255; each
//     thread-half does 4 rows; x rows wave-uniform -> s_load, Uw coalesced).
// A2: S[n][m] = sum_f Ww[f]*rcp(exp2(us[n][f]*y[m][f])+1)
//     alpha = Wsum - 2S monotone-DECREASING => reduce MIN of S; Wsum and
//     W_b cancel in max/softmax (shift-invariance). EXACT.
// Partials: rminp[b][mg][n] (min over 64 m), cminp[b][ns][m] (min over 8 n).
// ---------------------------------------------------------------------------
__global__ __launch_bounds__(512) void k2_fused(
    const float* __restrict__ x, const float* __restrict__ y,
    const float* __restrict__ Uw, const float* __restrict__ Ub,
    const float* __restrict__ Ww,
    float* __restrict__ rminp, float* __restrict__ cminp) {
  __shared__ float us[8][F_];        //  8 KB
  __shared__ float red[8][8][64];    // 16 KB  [n][fc][m-lane]
  __shared__ float sm[8][64];        //  2 KB

  const int tid  = threadIdx.x;
  const int mg   = blockIdx.x;   // 0..3
  const int ns   = blockIdx.y;   // 0..15
  const int b    = blockIdx.z;   // 0..7
  const int n0   = ns * 8;
  const int m0   = mg * 64;
  const int lane = tid & 63;
  const int w    = tid >> 6;
  const int fc   = __builtin_amdgcn_readfirstlane(w);   // 0..7 (32 f each)

  // ---- A1: recompute this block's 8 u rows into LDS ----
  {
    const int g  = tid & 255;
    const int rp = (tid >> 8) * 4;   // 0 or 4
    const float* __restrict__ uwr = Uw + (size_t)g * F_;
    const float* __restrict__ xr  = x + (size_t)(b * N_ + n0 + rp) * F_;
    float a0 = 0.f, a1 = 0.f, a2 = 0.f, a3 = 0.f;
#pragma unroll 4
    for (int f = 0; f < F_; f += 4) {
      const float4 wv = *(const float4*)&uwr[f];           // per-lane
      const float4 x0 = *(const float4*)&xr[0 * F_ + f];   // uniform -> s_load
      const float4 x1 = *(const float4*)&xr[1 * F_ + f];
      const float4 x2 = *(const float4*)&xr[2 * F_ + f];
      const float4 x3 = *(const float4*)&xr[3 * F_ + f];
      a0 = fmaf(wv.x, x0.x, a0); a0 = fmaf(wv.y, x0.y, a0);
      a0 = fmaf(wv.z, x0.z, a0); a0 = fmaf(wv.w, x0.w, a0);
      a1 = fmaf(wv.x, x1.x, a1); a1 = fmaf(wv.y, x1.y, a1);
      a1 = fmaf(wv.z, x1.z, a1); a1 = fmaf(wv.w, x1.w, a1);
      a2 = fmaf(wv.x, x2.x, a2); a2 = fmaf(wv.y, x2.y, a2);
      a2 = fmaf(wv.z, x2.z, a2); a2 = fmaf(wv.w, x2.w, a2);
      a3 = fmaf(wv.x, x3.x, a3); a3 = fmaf(wv.y, x3.y, a3);
      a3 = fmaf(wv.z, x3.z, a3); a3 = fmaf(wv.w, x3.w, a3);
    }
    const float ubv = Ub[g];
    us[rp + 0][g] = (a0 + ubv) * LOG2E2;
    us[rp + 1][g] = (a1 + ubv) * LOG2E2;
    us[rp + 2][g] = (a2 + ubv) * LOG2E2;
    us[rp + 3][g] = (a3 + ubv) * LOG2E2;
  }

  // ---- stage y chunk (32 VGPR) + wave-uniform Ww chunk (AFTER A1) ----
  float4 yv[8];
  float4 wwv[8];
  {
    const float* yr = y + ((size_t)(b * M_ + m0 + lane)) * F_ + fc * 32;
    const float* wr = Ww + fc * 32;
#pragma unroll
    for (int j = 0; j < 8; ++j) {
      yv[j]  = *(const float4*)&yr[4 * j];
      wwv[j] = *(const float4*)&wr[4 * j];
    }
  }
  __syncthreads();

  // ---- A2 hot loop: LDS broadcast + registers only ----
#define QUAD(nn, j, S0, S1)                                                              \
  do {                                                                                   \
    const float4 uv = *(const float4*)&us[nn][fc * 32 + 4 * (j)];                        \
    S0 = fmaf(wwv[j].x,                                                                  \
              __builtin_amdgcn_rcpf(__builtin_amdgcn_exp2f(uv.x * yv[j].x) + 1.f), S0);  \
    S1 = fmaf(wwv[j].y,                                                                  \
              __builtin_amdgcn_rcpf(__builtin_amdgcn_exp2f(uv.y * yv[j].y) + 1.f), S1);  \
    S0 = fmaf(wwv[j].z,                                                                  \
              __builtin_amdgcn_rcpf(__builtin_amdgcn_exp2f(uv.z * yv[j].z) + 1.f), S0);  \
    S1 = fmaf(wwv[j].w,                                                                  \
              __builtin_amdgcn_rcpf(__builtin_amdgcn_exp2f(uv.w * yv[j].w) + 1.f), S1);  \
  } while (0)

#define DO_N(nn, A)                                                                      \
  do {                                                                                   \
    float s0 = 0.f, s1 = 0.f;                                                            \
    QUAD(nn, 0, s0, s1); QUAD(nn, 1, s0, s1); QUAD(nn, 2, s0, s1); QUAD(nn, 3, s0, s1);  \
    QUAD(nn, 4, s0, s1); QUAD(nn, 5, s0, s1); QUAD(nn, 6, s0, s1); QUAD(nn, 7, s0, s1);  \
    A = s0 + s1;                                                                         \
  } while (0)

  float a0, a1, a2, a3, a4, a5, a6, a7;
  DO_N(0, a0); DO_N(1, a1); DO_N(2, a2); DO_N(3, a3);
  DO_N(4, a4); DO_N(5, a5); DO_N(6, a6); DO_N(7, a7);
#undef DO_N
#undef QUAD

  // ---- cross-fc sum ----
  red[0][fc][lane] = a0; red[1][fc][lane] = a1;
  red[2][fc][lane] = a2; red[3][fc][lane] = a3;
  red[4][fc][lane] = a4; red[5][fc][lane] = a5;
  red[6][fc][lane] = a6; red[7][fc][lane] = a7;
  __syncthreads();

  // wave w finalizes n = w over its 64 m-lanes
  float S = 0.f;
#pragma unroll
  for (int k = 0; k < 8; ++k) S += red[w][k][lane];

  // row-min partial (over this block's 64 m)
  float r = S;
#pragma unroll
  for (int s = 32; s; s >>= 1) r = fminf(r, __shfl_xor(r, s));
  if (lane == 0) rminp[((size_t)b * 4 + mg) * N_ + n0 + w] = r;

  // col-min partial (over this block's 8 n)
  sm[w][lane] = S;
  __syncthreads();
  if (w == 0) {
    float c = sm[0][lane];
#pragma unroll
    for (int k = 1; k < 8; ++k) c = fminf(c, sm[k][lane]);
    cminp[((size_t)b * 16 + ns) * M_ + m0 + lane] = c;
  }
}

// ---------------------------------------------------------------------------
// KB: finish. Grid (b, task): task 0 = x-softmax+x-pool, 1 = y-softmax+y-pool.
// Softmax inputs are -2 * min-partials (exact, shift-invariant).
// ---------------------------------------------------------------------------
__global__ __launch_bounds__(1024) void kb_final(
    const float* __restrict__ x, const float* __restrict__ y,
    const float* __restrict__ rminp, const float* __restrict__ cminp,
    float* __restrict__ out) {
  const int b = blockIdx.x;
  const int task = blockIdx.y;
  const int tid = threadIdx.x;
  const int wv = tid >> 6;
  __shared__ float wgt[M_];
  __shared__ float red[16];
  __shared__ float part[4][256];

  if (task == 0) {
    float rv = -INFINITY;
    if (tid < N_) {
      float v = INFINITY;
#pragma unroll
      for (int mg = 0; mg < 4; ++mg)
        v = fminf(v, rminp[((size_t)b * 4 + mg) * N_ + tid]);
      rv = -2.f * v;
    }
    float m1 = rv;
#pragma unroll
    for (int s = 32; s; s >>= 1) m1 = fmaxf(m1, __shfl_xor(m1, s));
    if ((tid & 63) == 0) red[wv] = m1;
    __syncthreads();
    m1 = red[0];
#pragma unroll
    for (int k = 1; k < 16; ++k) m1 = fmaxf(m1, red[k]);
    __syncthreads();
    const float e1 = (tid < N_) ? __expf(rv - m1) : 0.f;
    float s1 = e1;
#pragma unroll
    for (int s = 32; s; s >>= 1) s1 += __shfl_xor(s1, s);
    if ((tid & 63) == 0) red[wv] = s1;
    __syncthreads();
    s1 = 0.f;
#pragma unroll
    for (int k = 0; k < 16; ++k) s1 += red[k];
    if (tid < N_) wgt[tid] = e1 / s1;
    __syncthreads();

    const int q = tid >> 8, f = tid & 255;
    float accx = 0.f;
#pragma unroll 4
    for (int n = q; n < N_; n += 4)
      accx = fmaf(wgt[n], x[(size_t)(b * N_ + n) * F_ + f], accx);
    part[q][f] = accx;
    __syncthreads();
    if (tid < 256)
      out[b * (2 * F_) + f] = part[0][f] + part[1][f] + part[2][f] + part[3][f];
  } else {
    float cv = -INFINITY;
    if (tid < M_) {
      float c = INFINITY;
#pragma unroll
      for (int ns = 0; ns < 16; ++ns)
        c = fminf(c, cminp[((size_t)b * 16 + ns) * M_ + tid]);
      cv = -2.f * c;
    }
    float m2 = cv;
#pragma unroll
    for (int s = 32; s; s >>= 1) m2 = fmaxf(m2, __shfl_xor(m2, s));
    if ((tid & 63) == 0) red[wv] = m2;
    __syncthreads();
    m2 = red[0];
#pragma unroll
    for (int k = 1; k < 16; ++k) m2 = fmaxf(m2, red[k]);
    __syncthreads();
    const float e2 = (tid < M_) ? __expf(cv - m2) : 0.f;
    float s2 = e2;
#pragma unroll
    for (int s = 32; s; s >>= 1) s2 += __shfl_xor(s2, s);
    if ((tid & 63) == 0) red[wv] = s2;
    __syncthreads();
    s2 = 0.f;
#pragma unroll
    for (int k = 0; k < 16; ++k) s2 += red[k];
    if (tid < M_) wgt[tid] = e2 / s2;
    __syncthreads();

    const int q = tid >> 8, f = tid & 255;
    float accy = 0.f;
#pragma unroll 4
    for (int m = q; m < M_; m += 4)
      accy = fmaf(wgt[m], y[(size_t)(b * M_ + m) * F_ + f], accy);
    part[q][f] = accy;
    __syncthreads();
    if (tid < 256)
      out[b * (2 * F_) + F_ + f] =
          part[0][f] + part[1][f] + part[2][f] + part[3][f];
  }
}

// ---------------------------------------------------------------------------
extern "C" void kernel_launch(void* const* d_in, const int* in_sizes, int n_in,
                              void* d_out, int out_size, void* d_ws, size_t ws_size,
                              hipStream_t stream) {
  (void)in_sizes; (void)n_in; (void)out_size; (void)ws_size;
  const float* x  = (const float*)d_in[0];
  const float* y  = (const float*)d_in[1];
  const float* Uw = (const float*)d_in[2];
  const float* Ub = (const float*)d_in[3];
  const float* Ww = (const float*)d_in[4];
  // d_in[5] (W_b) unused: max/softmax pipeline is shift-invariant.

  float* rminp = (float*)d_ws;              // [B][4][N]    4096 f
  float* cminp = rminp + B_ * 4 * N_;       // [B][16][M]  32768 f
  float* outp  = (float*)d_out;

  k2_fused<<<dim3(4, 16, B_), 512, 0, stream>>>(x, y, Uw, Ub, Ww, rminp, cminp);
  kb_final<<<dim3(B_, 2), 1024, 0, stream>>>(x, y, rminp, cminp, outp);
}

// Round 12
// 79.071 us; speedup vs baseline: 1.1129x; 1.0421x over previous
//
#include <hip/hip_runtime.h>
#include <math.h>

#define B_ 8
#define N_ 128
#define M_ 256
#define F_ 256

#define LOG2E2 2.8853900817779268f  // 2*log2(e)

// ---------------------------------------------------------------------------
// K2F v3: fused u-recompute + bilinear-tanh partials, designed to FIT the
// compiler's ~64-VGPR occupancy budget (rounds 8-11 lesson: 512-thread +
// ~27KB-LDS kernels get VGPR-clamped to 32-64; oversized staging arrays are
// silently re-read from global in the hot loop -> 80 us).
//   Register plan: yv[8] float4 = 32 + 8 named accs + addressing  (~55).
//   Ww lives in LDS (broadcast reads), NOT registers.
//   A1 uses #pragma unroll 2 (<=10 float4 in flight).
//   NO __launch_bounds__ (empirically least clamped).
//
// Grid (mg 0..3, ns 0..15, b 0..7) = 512 blocks, 512 threads (8 waves).
// Block owns n rows n0=ns*8..+7, m cols m0=mg*64..+63, all 256 f.
//   wave w = f-chunk fc (32 f);  lane = m offset within mg's 64 m.
//
// A1: us[r][g] = (x[n0+r,:].Uw[g,:] + Ub[g])*2log2e  (g = tid&255; each
//     thread-half does 4 rows; x rows wave-uniform -> s_load, Uw coalesced).
// A2: S[n][m] = sum_f Ww[f]*rcp(exp2(us[n][f]*y[m][f])+1)
//     alpha = Wsum - 2S monotone-DECREASING => reduce MIN of S; Wsum and
//     W_b cancel in max/softmax (shift-invariance). EXACT.
// Partials: rminp[b][mg][n] (min over 64 m), cminp[b][ns][m] (min over 8 n).
// ---------------------------------------------------------------------------
__global__ void k2_fused(const float* __restrict__ x,
                         const float* __restrict__ y,
                         const float* __restrict__ Uw,
                         const float* __restrict__ Ub,
                         const float* __restrict__ Ww,
                         float* __restrict__ rminp,
                         float* __restrict__ cminp) {
  __shared__ float us[8][F_];        //  8 KB
  __shared__ float ww[F_];           //  1 KB
  __shared__ float red[8][8][64];    // 16 KB  [n][fc][m-lane]
  __shared__ float sm[8][64];        //  2 KB

  const int tid  = threadIdx.x;
  const int mg   = blockIdx.x;   // 0..3
  const int ns   = blockIdx.y;   // 0..15
  const int b    = blockIdx.z;   // 0..7
  const int n0   = ns * 8;
  const int m0   = mg * 64;
  const int lane = tid & 63;
  const int w    = tid >> 6;
  const int fc   = __builtin_amdgcn_readfirstlane(w);   // 0..7 (32 f each)

  // ---- A1: recompute this block's 8 u rows into LDS (low reg pressure) ----
  {
    const int g  = tid & 255;
    const int rp = (tid >> 8) * 4;   // 0 or 4
    const float* __restrict__ uwr = Uw + (size_t)g * F_;
    const float* __restrict__ xr  = x + (size_t)(b * N_ + n0 + rp) * F_;
    float a0 = 0.f, a1 = 0.f, a2 = 0.f, a3 = 0.f;
#pragma unroll 2
    for (int f = 0; f < F_; f += 4) {
      const float4 wv = *(const float4*)&uwr[f];           // per-lane
      const float4 x0 = *(const float4*)&xr[0 * F_ + f];   // uniform -> s_load
      const float4 x1 = *(const float4*)&xr[1 * F_ + f];
      const float4 x2 = *(const float4*)&xr[2 * F_ + f];
      const float4 x3 = *(const float4*)&xr[3 * F_ + f];
      a0 = fmaf(wv.x, x0.x, a0); a0 = fmaf(wv.y, x0.y, a0);
      a0 = fmaf(wv.z, x0.z, a0); a0 = fmaf(wv.w, x0.w, a0);
      a1 = fmaf(wv.x, x1.x, a1); a1 = fmaf(wv.y, x1.y, a1);
      a1 = fmaf(wv.z, x1.z, a1); a1 = fmaf(wv.w, x1.w, a1);
      a2 = fmaf(wv.x, x2.x, a2); a2 = fmaf(wv.y, x2.y, a2);
      a2 = fmaf(wv.z, x2.z, a2); a2 = fmaf(wv.w, x2.w, a2);
      a3 = fmaf(wv.x, x3.x, a3); a3 = fmaf(wv.y, x3.y, a3);
      a3 = fmaf(wv.z, x3.z, a3); a3 = fmaf(wv.w, x3.w, a3);
    }
    const float ubv = Ub[g];
    us[rp + 0][g] = (a0 + ubv) * LOG2E2;
    us[rp + 1][g] = (a1 + ubv) * LOG2E2;
    us[rp + 2][g] = (a2 + ubv) * LOG2E2;
    us[rp + 3][g] = (a3 + ubv) * LOG2E2;
  }
  // stage Ww into LDS (one wave's worth of float4s)
  if (tid < 64) *(float4*)&ww[tid * 4] = *(const float4*)&Ww[tid * 4];

  // ---- stage y chunk into registers (32 VGPR) ----
  float4 yv[8];
  {
    const float* yr = y + ((size_t)(b * M_ + m0 + lane)) * F_ + fc * 32;
#pragma unroll
    for (int j = 0; j < 8; ++j) yv[j] = *(const float4*)&yr[4 * j];
  }
  __syncthreads();

  // ---- A2 hot loop: LDS broadcasts (us, ww) + yv registers ----
#define QUAD(nn, j, S0, S1)                                                              \
  do {                                                                                   \
    const float4 uv  = *(const float4*)&us[nn][fc * 32 + 4 * (j)];                       \
    const float4 wv4 = *(const float4*)&ww[fc * 32 + 4 * (j)];                           \
    S0 = fmaf(wv4.x,                                                                     \
              __builtin_amdgcn_rcpf(__builtin_amdgcn_exp2f(uv.x * yv[j].x) + 1.f), S0);  \
    S1 = fmaf(wv4.y,                                                                     \
              __builtin_amdgcn_rcpf(__builtin_amdgcn_exp2f(uv.y * yv[j].y) + 1.f), S1);  \
    S0 = fmaf(wv4.z,                                                                     \
              __builtin_amdgcn_rcpf(__builtin_amdgcn_exp2f(uv.z * yv[j].z) + 1.f), S0);  \
    S1 = fmaf(wv4.w,                                                                     \
              __builtin_amdgcn_rcpf(__builtin_amdgcn_exp2f(uv.w * yv[j].w) + 1.f), S1);  \
  } while (0)

#define DO_N(nn, A)                                                                      \
  do {                                                                                   \
    float s0 = 0.f, s1 = 0.f;                                                            \
    QUAD(nn, 0, s0, s1); QUAD(nn, 1, s0, s1); QUAD(nn, 2, s0, s1); QUAD(nn, 3, s0, s1);  \
    QUAD(nn, 4, s0, s1); QUAD(nn, 5, s0, s1); QUAD(nn, 6, s0, s1); QUAD(nn, 7, s0, s1);  \
    A = s0 + s1;                                                                         \
  } while (0)

  float a0, a1, a2, a3, a4, a5, a6, a7;
  DO_N(0, a0); DO_N(1, a1); DO_N(2, a2); DO_N(3, a3);
  DO_N(4, a4); DO_N(5, a5); DO_N(6, a6); DO_N(7, a7);
#undef DO_N
#undef QUAD

  // ---- cross-fc sum ----
  red[0][fc][lane] = a0; red[1][fc][lane] = a1;
  red[2][fc][lane] = a2; red[3][fc][lane] = a3;
  red[4][fc][lane] = a4; red[5][fc][lane] = a5;
  red[6][fc][lane] = a6; red[7][fc][lane] = a7;
  __syncthreads();

  // wave w finalizes n = w over its 64 m-lanes
  float S = 0.f;
#pragma unroll
  for (int k = 0; k < 8; ++k) S += red[w][k][lane];

  // row-min partial (over this block's 64 m)
  float r = S;
#pragma unroll
  for (int s = 32; s; s >>= 1) r = fminf(r, __shfl_xor(r, s));
  if (lane == 0) rminp[((size_t)b * 4 + mg) * N_ + n0 + w] = r;

  // col-min partial (over this block's 8 n)
  sm[w][lane] = S;
  __syncthreads();
  if (w == 0) {
    float c = sm[0][lane];
#pragma unroll
    for (int k = 1; k < 8; ++k) c = fminf(c, sm[k][lane]);
    cminp[((size_t)b * 16 + ns) * M_ + m0 + lane] = c;
  }
}

// ---------------------------------------------------------------------------
// KB: finish. Grid (b, task): task 0 = x-softmax+x-pool, 1 = y-softmax+y-pool.
// Softmax inputs are -2 * min-partials (exact, shift-invariant).
// ---------------------------------------------------------------------------
__global__ __launch_bounds__(1024) void kb_final(
    const float* __restrict__ x, const float* __restrict__ y,
    const float* __restrict__ rminp, const float* __restrict__ cminp,
    float* __restrict__ out) {
  const int b = blockIdx.x;
  const int task = blockIdx.y;
  const int tid = threadIdx.x;
  const int wv = tid >> 6;
  __shared__ float wgt[M_];
  __shared__ float red[16];
  __shared__ float part[4][256];

  if (task == 0) {
    float rv = -INFINITY;
    if (tid < N_) {
      float v = INFINITY;
#pragma unroll
      for (int mg = 0; mg < 4; ++mg)
        v = fminf(v, rminp[((size_t)b * 4 + mg) * N_ + tid]);
      rv = -2.f * v;
    }
    float m1 = rv;
#pragma unroll
    for (int s = 32; s; s >>= 1) m1 = fmaxf(m1, __shfl_xor(m1, s));
    if ((tid & 63) == 0) red[wv] = m1;
    __syncthreads();
    m1 = red[0];
#pragma unroll
    for (int k = 1; k < 16; ++k) m1 = fmaxf(m1, red[k]);
    __syncthreads();
    const float e1 = (tid < N_) ? __expf(rv - m1) : 0.f;
    float s1 = e1;
#pragma unroll
    for (int s = 32; s; s >>= 1) s1 += __shfl_xor(s1, s);
    if ((tid & 63) == 0) red[wv] = s1;
    __syncthreads();
    s1 = 0.f;
#pragma unroll
    for (int k = 0; k < 16; ++k) s1 += red[k];
    if (tid < N_) wgt[tid] = e1 / s1;
    __syncthreads();

    const int q = tid >> 8, f = tid & 255;
    float accx = 0.f;
#pragma unroll 4
    for (int n = q; n < N_; n += 4)
      accx = fmaf(wgt[n], x[(size_t)(b * N_ + n) * F_ + f], accx);
    part[q][f] = accx;
    __syncthreads();
    if (tid < 256)
      out[b * (2 * F_) + f] = part[0][f] + part[1][f] + part[2][f] + part[3][f];
  } else {
    float cv = -INFINITY;
    if (tid < M_) {
      float c = INFINITY;
#pragma unroll
      for (int ns = 0; ns < 16; ++ns)
        c = fminf(c, cminp[((size_t)b * 16 + ns) * M_ + tid]);
      cv = -2.f * c;
    }
    float m2 = cv;
#pragma unroll
    for (int s = 32; s; s >>= 1) m2 = fmaxf(m2, __shfl_xor(m2, s));
    if ((tid & 63) == 0) red[wv] = m2;
    __syncthreads();
    m2 = red[0];
#pragma unroll
    for (int k = 1; k < 16; ++k) m2 = fmaxf(m2, red[k]);
    __syncthreads();
    const float e2 = (tid < M_) ? __expf(cv - m2) : 0.f;
    float s2 = e2;
#pragma unroll
    for (int s = 32; s; s >>= 1) s2 += __shfl_xor(s2, s);
    if ((tid & 63) == 0) red[wv] = s2;
    __syncthreads();
    s2 = 0.f;
#pragma unroll
    for (int k = 0; k < 16; ++k) s2 += red[k];
    if (tid < M_) wgt[tid] = e2 / s2;
    __syncthreads();

    const int q = tid >> 8, f = tid & 255;
    float accy = 0.f;
#pragma unroll 4
    for (int m = q; m < M_; m += 4)
      accy = fmaf(wgt[m], y[(size_t)(b * M_ + m) * F_ + f], accy);
    part[q][f] = accy;
    __syncthreads();
    if (tid < 256)
      out[b * (2 * F_) + F_ + f] =
          part[0][f] + part[1][f] + part[2][f] + part[3][f];
  }
}

// ---------------------------------------------------------------------------
extern "C" void kernel_launch(void* const* d_in, const int* in_sizes, int n_in,
                              void* d_out, int out_size, void* d_ws, size_t ws_size,
                              hipStream_t stream) {
  (void)in_sizes; (void)n_in; (void)out_size; (void)ws_size;
  const float* x  = (const float*)d_in[0];
  const float* y  = (const float*)d_in[1];
  const float* Uw = (const float*)d_in[2];
  const float* Ub = (const float*)d_in[3];
  const float* Ww = (const float*)d_in[4];
  // d_in[5] (W_b) unused: max/softmax pipeline is shift-invariant.

  float* rminp = (float*)d_ws;              // [B][4][N]    4096 f
  float* cminp = rminp + B_ * 4 * N_;       // [B][16][M]  32768 f
  float* outp  = (float*)d_out;

  k2_fused<<<dim3(4, 16, B_), 512, 0, stream>>>(x, y, Uw, Ub, Ww, rminp, cminp);
  kb_final<<<dim3(B_, 2), 1024, 0, stream>>>(x, y, rminp, cminp, outp);
}

// Round 13
// 35.712 us; speedup vs baseline: 2.4641x; 2.2142x over previous
//
#include <hip/hip_runtime.h>
#include <math.h>

#define B_ 8
#define N_ 128
#define M_ 256
#define F_ 256

#define LOG2E2 2.8853900817779268f  // 2*log2(e)

// ---------------------------------------------------------------------------
// K1-lite: u[r][g] = (x[r,:].Uw[g,:] + Ub[g]) * 2log2e,  r = b*N+n (1024 rows).
// No LDS, no tiling: lane = output column g (256 lanes), 4 rows per block.
// x rows are block-uniform -> scalar-cache s_load_dwordx4; Uw per-lane float4
// (16B/lane); output stores coalesced. ~20 VGPR -> immune to the r8-r12
// occupancy/spill trap. Replaces the LDS-bound tiled GEMM (~13 us -> ~3 us):
// the +1-padded tiles forced scalar ds_read_b32 (6 per 8 FMA) on 128 CUs.
// ---------------------------------------------------------------------------
__global__ __launch_bounds__(256) void k1_lite(const float* __restrict__ x,
                                               const float* __restrict__ Uw,
                                               const float* __restrict__ Ub,
                                               float* __restrict__ u) {
  const int g  = threadIdx.x;          // output column
  const int r0 = blockIdx.x * 4;       // 4 rows of the 1024 flat rows
  const float* __restrict__ uwr = Uw + (size_t)g * F_;
  const float* __restrict__ xr  = x + (size_t)r0 * F_;   // block-uniform

  float a0 = 0.f, a1 = 0.f, a2 = 0.f, a3 = 0.f;
#pragma unroll 4
  for (int f = 0; f < F_; f += 4) {
    const float4 wv = *(const float4*)&uwr[f];           // per-lane
    const float4 x0 = *(const float4*)&xr[0 * F_ + f];   // uniform -> s_load
    const float4 x1 = *(const float4*)&xr[1 * F_ + f];
    const float4 x2 = *(const float4*)&xr[2 * F_ + f];
    const float4 x3 = *(const float4*)&xr[3 * F_ + f];
    a0 = fmaf(wv.x, x0.x, a0); a0 = fmaf(wv.y, x0.y, a0);
    a0 = fmaf(wv.z, x0.z, a0); a0 = fmaf(wv.w, x0.w, a0);
    a1 = fmaf(wv.x, x1.x, a1); a1 = fmaf(wv.y, x1.y, a1);
    a1 = fmaf(wv.z, x1.z, a1); a1 = fmaf(wv.w, x1.w, a1);
    a2 = fmaf(wv.x, x2.x, a2); a2 = fmaf(wv.y, x2.y, a2);
    a2 = fmaf(wv.z, x2.z, a2); a2 = fmaf(wv.w, x2.w, a2);
    a3 = fmaf(wv.x, x3.x, a3); a3 = fmaf(wv.y, x3.y, a3);
    a3 = fmaf(wv.z, x3.z, a3); a3 = fmaf(wv.w, x3.w, a3);
  }
  const float ubv = Ub[g];
  u[(size_t)(r0 + 0) * F_ + g] = (a0 + ubv) * LOG2E2;
  u[(size_t)(r0 + 1) * F_ + g] = (a1 + ubv) * LOG2E2;
  u[(size_t)(r0 + 2) * F_ + g] = (a2 + ubv) * LOG2E2;
  u[(size_t)(r0 + 3) * F_ + g] = (a3 + ubv) * LOG2E2;
}

// ---------------------------------------------------------------------------
// K2 (round-9 proven-clean version, UNCHANGED): occupancy-first, spill-free.
// Grid (mg 0..3, ns 0..15, b 0..7) = 512 blocks, 512 threads (8 waves).
// NO __launch_bounds__ (r8/r11: any bounds variant clamps VGPR -> spill).
//   wave w = f-chunk fc (32 f);  lane = m offset within mg's 64 m.
// u rows staged once in LDS (broadcast reads, conflict-free); y chunk in
// yv[8] float4 (32 VGPR, static idx); Ww chunk wave-uniform; 8 NAMED accs.
// S[n][m] = sum_f Ww[f]*rcp(exp2(us[n][f]*y[m][f])+1);  alpha = Wsum - 2S
// monotone-decreasing => reduce MIN of S (Wsum, W_b cancel in max/softmax).
// Partials: rminp[b][mg][n] (min over 64 m), cminp[b][ns][m] (min over 8 n).
// ---------------------------------------------------------------------------
__global__ void k2_alpha(const float* __restrict__ u,
                         const float* __restrict__ y,
                         const float* __restrict__ Ww,
                         float* __restrict__ rminp,
                         float* __restrict__ cminp) {
  __shared__ float us[8][F_];        //  8 KB
  __shared__ float red[8][8][64];    // 16 KB  [n][fc][m-lane]
  __shared__ float sm[8][64];        //  2 KB

  const int tid  = threadIdx.x;
  const int mg   = blockIdx.x;   // 0..3
  const int ns   = blockIdx.y;   // 0..15
  const int b    = blockIdx.z;   // 0..7
  const int n0   = ns * 8;
  const int m0   = mg * 64;
  const int lane = tid & 63;
  const int w    = tid >> 6;
  const int fc   = __builtin_amdgcn_readfirstlane(w);   // 0..7 (32 f each)

  // ---- stage this block's 8 u rows into LDS (coalesced, once) ----
  {
    const int r = tid >> 6, c = (tid & 63) * 4;
    *(float4*)&us[r][c] =
        *(const float4*)&u[(size_t)(b * N_ + n0 + r) * F_ + c];
  }

  // ---- per-thread y chunk (32 VGPR) + wave-uniform Ww chunk ----
  float4 yv[8];
  float4 wwv[8];
  {
    const float* yr = y + ((size_t)(b * M_ + m0 + lane)) * F_ + fc * 32;
    const float* wr = Ww + fc * 32;
#pragma unroll
    for (int j = 0; j < 8; ++j) {
      yv[j]  = *(const float4*)&yr[4 * j];
      wwv[j] = *(const float4*)&wr[4 * j];
    }
  }
  __syncthreads();

  // ---- hot loop: LDS broadcast + registers only ----
#define QUAD(nn, j, S0, S1)                                                              \
  do {                                                                                   \
    const float4 uv = *(const float4*)&us[nn][fc * 32 + 4 * (j)];                        \
    S0 = fmaf(wwv[j].x,                                                                  \
              __builtin_amdgcn_rcpf(__builtin_amdgcn_exp2f(uv.x * yv[j].x) + 1.f), S0);  \
    S1 = fmaf(wwv[j].y,                                                                  \
              __builtin_amdgcn_rcpf(__builtin_amdgcn_exp2f(uv.y * yv[j].y) + 1.f), S1);  \
    S0 = fmaf(wwv[j].z,                                                                  \
              __builtin_amdgcn_rcpf(__builtin_amdgcn_exp2f(uv.z * yv[j].z) + 1.f), S0);  \
    S1 = fmaf(wwv[j].w,                                                                  \
              __builtin_amdgcn_rcpf(__builtin_amdgcn_exp2f(uv.w * yv[j].w) + 1.f), S1);  \
  } while (0)

#define DO_N(nn, A)                                                                      \
  do {                                                                                   \
    float s0 = 0.f, s1 = 0.f;                                                            \
    QUAD(nn, 0, s0, s1); QUAD(nn, 1, s0, s1); QUAD(nn, 2, s0, s1); QUAD(nn, 3, s0, s1);  \
    QUAD(nn, 4, s0, s1); QUAD(nn, 5, s0, s1); QUAD(nn, 6, s0, s1); QUAD(nn, 7, s0, s1);  \
    A = s0 + s1;                                                                         \
  } while (0)

  float a0, a1, a2, a3, a4, a5, a6, a7;
  DO_N(0, a0); DO_N(1, a1); DO_N(2, a2); DO_N(3, a3);
  DO_N(4, a4); DO_N(5, a5); DO_N(6, a6); DO_N(7, a7);
#undef DO_N
#undef QUAD

  // ---- cross-fc sum ----
  red[0][fc][lane] = a0; red[1][fc][lane] = a1;
  red[2][fc][lane] = a2; red[3][fc][lane] = a3;
  red[4][fc][lane] = a4; red[5][fc][lane] = a5;
  red[6][fc][lane] = a6; red[7][fc][lane] = a7;
  __syncthreads();

  // wave w finalizes n = w over its 64 m-lanes
  float S = 0.f;
#pragma unroll
  for (int k = 0; k < 8; ++k) S += red[w][k][lane];

  // row-min partial (over this block's 64 m)
  float r = S;
#pragma unroll
  for (int s = 32; s; s >>= 1) r = fminf(r, __shfl_xor(r, s));
  if (lane == 0) rminp[((size_t)b * 4 + mg) * N_ + n0 + w] = r;

  // col-min partial (over this block's 8 n)
  sm[w][lane] = S;
  __syncthreads();
  if (w == 0) {
    float c = sm[0][lane];
#pragma unroll
    for (int k = 1; k < 8; ++k) c = fminf(c, sm[k][lane]);
    cminp[((size_t)b * 16 + ns) * M_ + m0 + lane] = c;
  }
}

// ---------------------------------------------------------------------------
// KB: finish. Grid (b, task): task 0 = x-softmax+x-pool, 1 = y-softmax+y-pool.
// Softmax inputs are -2 * min-partials (exact, shift-invariant).
// ---------------------------------------------------------------------------
__global__ __launch_bounds__(1024) void kb_final(
    const float* __restrict__ x, const float* __restrict__ y,
    const float* __restrict__ rminp, const float* __restrict__ cminp,
    float* __restrict__ out) {
  const int b = blockIdx.x;
  const int task = blockIdx.y;
  const int tid = threadIdx.x;
  const int wv = tid >> 6;
  __shared__ float wgt[M_];
  __shared__ float red[16];
  __shared__ float part[4][256];

  if (task == 0) {
    float rv = -INFINITY;
    if (tid < N_) {
      float v = INFINITY;
#pragma unroll
      for (int mg = 0; mg < 4; ++mg)
        v = fminf(v, rminp[((size_t)b * 4 + mg) * N_ + tid]);
      rv = -2.f * v;
    }
    float m1 = rv;
#pragma unroll
    for (int s = 32; s; s >>= 1) m1 = fmaxf(m1, __shfl_xor(m1, s));
    if ((tid & 63) == 0) red[wv] = m1;
    __syncthreads();
    m1 = red[0];
#pragma unroll
    for (int k = 1; k < 16; ++k) m1 = fmaxf(m1, red[k]);
    __syncthreads();
    const float e1 = (tid < N_) ? __expf(rv - m1) : 0.f;
    float s1 = e1;
#pragma unroll
    for (int s = 32; s; s >>= 1) s1 += __shfl_xor(s1, s);
    if ((tid & 63) == 0) red[wv] = s1;
    __syncthreads();
    s1 = 0.f;
#pragma unroll
    for (int k = 0; k < 16; ++k) s1 += red[k];
    if (tid < N_) wgt[tid] = e1 / s1;
    __syncthreads();

    const int q = tid >> 8, f = tid & 255;
    float accx = 0.f;
#pragma unroll 4
    for (int n = q; n < N_; n += 4)
      accx = fmaf(wgt[n], x[(size_t)(b * N_ + n) * F_ + f], accx);
    part[q][f] = accx;
    __syncthreads();
    if (tid < 256)
      out[b * (2 * F_) + f] = part[0][f] + part[1][f] + part[2][f] + part[3][f];
  } else {
    float cv = -INFINITY;
    if (tid < M_) {
      float c = INFINITY;
#pragma unroll
      for (int ns = 0; ns < 16; ++ns)
        c = fminf(c, cminp[((size_t)b * 16 + ns) * M_ + tid]);
      cv = -2.f * c;
    }
    float m2 = cv;
#pragma unroll
    for (int s = 32; s; s >>= 1) m2 = fmaxf(m2, __shfl_xor(m2, s));
    if ((tid & 63) == 0) red[wv] = m2;
    __syncthreads();
    m2 = red[0];
#pragma unroll
    for (int k = 1; k < 16; ++k) m2 = fmaxf(m2, red[k]);
    __syncthreads();
    const float e2 = (tid < M_) ? __expf(cv - m2) : 0.f;
    float s2 = e2;
#pragma unroll
    for (int s = 32; s; s >>= 1) s2 += __shfl_xor(s2, s);
    if ((tid & 63) == 0) red[wv] = s2;
    __syncthreads();
    s2 = 0.f;
#pragma unroll
    for (int k = 0; k < 16; ++k) s2 += red[k];
    if (tid < M_) wgt[tid] = e2 / s2;
    __syncthreads();

    const int q = tid >> 8, f = tid & 255;
    float accy = 0.f;
#pragma unroll 4
    for (int m = q; m < M_; m += 4)
      accy = fmaf(wgt[m], y[(size_t)(b * M_ + m) * F_ + f], accy);
    part[q][f] = accy;
    __syncthreads();
    if (tid < 256)
      out[b * (2 * F_) + F_ + f] =
          part[0][f] + part[1][f] + part[2][f] + part[3][f];
  }
}

// ---------------------------------------------------------------------------
extern "C" void kernel_launch(void* const* d_in, const int* in_sizes, int n_in,
                              void* d_out, int out_size, void* d_ws, size_t ws_size,
                              hipStream_t stream) {
  (void)in_sizes; (void)n_in; (void)out_size; (void)ws_size;
  const float* x  = (const float*)d_in[0];
  const float* y  = (const float*)d_in[1];
  const float* Uw = (const float*)d_in[2];
  const float* Ub = (const float*)d_in[3];
  const float* Ww = (const float*)d_in[4];
  // d_in[5] (W_b) unused: max/softmax pipeline is shift-invariant.

  float* u     = (float*)d_ws;                 // [B][N][F]    262144 f
  float* rminp = u + B_ * N_ * F_;             // [B][4][N]      4096 f
  float* cminp = rminp + B_ * 4 * N_;          // [B][16][M]   32768 f
  float* outp  = (float*)d_out;

  k1_lite<<<dim3((B_ * N_) / 4), 256, 0, stream>>>(x, Uw, Ub, u);
  k2_alpha<<<dim3(4, 16, B_), 512, 0, stream>>>(u, y, Ww, rminp, cminp);
  kb_final<<<dim3(B_, 2), 1024, 0, stream>>>(x, y, rminp, cminp, outp);
}

// Round 14
// 35.560 us; speedup vs baseline: 2.4746x; 1.0043x over previous
//
#include <hip/hip_runtime.h>
#include <math.h>

#define B_ 8
#define N_ 128
#define M_ 256
#define F_ 256

#define LOG2E2 2.8853900817779268f  // 2*log2(e)

// ---------------------------------------------------------------------------
// K1-lite (r13, unchanged): u[r][g] = (x[r,:].Uw[g,:] + Ub[g]) * 2log2e.
// No LDS; lane = output column g; 4 rows/block; x rows via scalar cache.
// ---------------------------------------------------------------------------
__global__ __launch_bounds__(256) void k1_lite(const float* __restrict__ x,
                                               const float* __restrict__ Uw,
                                               const float* __restrict__ Ub,
                                               float* __restrict__ u) {
  const int g  = threadIdx.x;
  const int r0 = blockIdx.x * 4;
  const float* __restrict__ uwr = Uw + (size_t)g * F_;
  const float* __restrict__ xr  = x + (size_t)r0 * F_;

  float a0 = 0.f, a1 = 0.f, a2 = 0.f, a3 = 0.f;
#pragma unroll 4
  for (int f = 0; f < F_; f += 4) {
    const float4 wv = *(const float4*)&uwr[f];
    const float4 x0 = *(const float4*)&xr[0 * F_ + f];
    const float4 x1 = *(const float4*)&xr[1 * F_ + f];
    const float4 x2 = *(const float4*)&xr[2 * F_ + f];
    const float4 x3 = *(const float4*)&xr[3 * F_ + f];
    a0 = fmaf(wv.x, x0.x, a0); a0 = fmaf(wv.y, x0.y, a0);
    a0 = fmaf(wv.z, x0.z, a0); a0 = fmaf(wv.w, x0.w, a0);
    a1 = fmaf(wv.x, x1.x, a1); a1 = fmaf(wv.y, x1.y, a1);
    a1 = fmaf(wv.z, x1.z, a1); a1 = fmaf(wv.w, x1.w, a1);
    a2 = fmaf(wv.x, x2.x, a2); a2 = fmaf(wv.y, x2.y, a2);
    a2 = fmaf(wv.z, x2.z, a2); a2 = fmaf(wv.w, x2.w, a2);
    a3 = fmaf(wv.x, x3.x, a3); a3 = fmaf(wv.y, x3.y, a3);
    a3 = fmaf(wv.z, x3.z, a3); a3 = fmaf(wv.w, x3.w, a3);
  }
  const float ubv = Ub[g];
  u[(size_t)(r0 + 0) * F_ + g] = (a0 + ubv) * LOG2E2;
  u[(size_t)(r0 + 1) * F_ + g] = (a1 + ubv) * LOG2E2;
  u[(size_t)(r0 + 2) * F_ + g] = (a2 + ubv) * LOG2E2;
  u[(size_t)(r0 + 3) * F_ + g] = (a3 + ubv) * LOG2E2;
}

// ---------------------------------------------------------------------------
// K2 v8: r13 hot loop + COALESCED y staging via LDS bounce.
// r13's per-lane y loads had lane-stride 1KB -> 64 transactions per
// global_load_dwordx4 (~3.4 us serialized TA per CU). Now: cooperative
// coalesced load of the 64x256 y tile into padded ys[64][132] (two f-halves),
// then each thread ds_read_b128s its row chunk into the same yv[8] registers.
// Everything else (register plan, hot loop, reductions) identical to r13.
// NO __launch_bounds__ (r8/r11: bounds variants clamp VGPR -> spill).
// ---------------------------------------------------------------------------
__global__ void k2_alpha(const float* __restrict__ u,
                         const float* __restrict__ y,
                         const float* __restrict__ Ww,
                         float* __restrict__ rminp,
                         float* __restrict__ cminp) {
  __shared__ float us[8][F_];        //  8 KB
  __shared__ float ys[64][132];      // 33.8 KB (128 f + 4 pad per row)
  __shared__ float red[8][8][64];    // 16 KB  [n][fc][m-lane]
  __shared__ float sm[8][64];        //  2 KB

  const int tid  = threadIdx.x;
  const int mg   = blockIdx.x;   // 0..3
  const int ns   = blockIdx.y;   // 0..15
  const int b    = blockIdx.z;   // 0..7
  const int n0   = ns * 8;
  const int m0   = mg * 64;
  const int lane = tid & 63;
  const int w    = tid >> 6;
  const int fc   = __builtin_amdgcn_readfirstlane(w);   // 0..7 (32 f each)

  // ---- stage this block's 8 u rows into LDS (coalesced, once) ----
  {
    const int r = tid >> 6, c = (tid & 63) * 4;
    *(float4*)&us[r][c] =
        *(const float4*)&u[(size_t)(b * N_ + n0 + r) * F_ + c];
  }
  // ---- wave-uniform Ww chunk ----
  float4 wwv[8];
  {
    const float* wr = Ww + fc * 32;
#pragma unroll
    for (int j = 0; j < 8; ++j) wwv[j] = *(const float4*)&wr[4 * j];
  }

  // ---- y tile via coalesced LDS bounce, two 128-f halves ----
  float4 yv[8];
  const float* __restrict__ ybase = y + (size_t)(b * M_ + m0) * F_;
  // half 0: f 0..127
#pragma unroll
  for (int k = 0; k < 4; ++k) {
    const int flat = tid + k * 512;          // 0..2047
    const int row = flat >> 5, col = (flat & 31) * 4;
    *(float4*)&ys[row][col] = *(const float4*)&ybase[(size_t)row * F_ + col];
  }
  __syncthreads();
  if (w < 4) {
    const int base = fc * 32;
#pragma unroll
    for (int j = 0; j < 8; ++j) yv[j] = *(const float4*)&ys[lane][base + 4 * j];
  }
  __syncthreads();
  // half 1: f 128..255
#pragma unroll
  for (int k = 0; k < 4; ++k) {
    const int flat = tid + k * 512;
    const int row = flat >> 5, col = (flat & 31) * 4;
    *(float4*)&ys[row][col] =
        *(const float4*)&ybase[(size_t)row * F_ + 128 + col];
  }
  __syncthreads();
  if (w >= 4) {
    const int base = (fc - 4) * 32;
#pragma unroll
    for (int j = 0; j < 8; ++j) yv[j] = *(const float4*)&ys[lane][base + 4 * j];
  }
  __syncthreads();

  // ---- hot loop: LDS broadcast + registers only (r13-identical) ----
#define QUAD(nn, j, S0, S1)                                                              \
  do {                                                                                   \
    const float4 uv = *(const float4*)&us[nn][fc * 32 + 4 * (j)];                        \
    S0 = fmaf(wwv[j].x,                                                                  \
              __builtin_amdgcn_rcpf(__builtin_amdgcn_exp2f(uv.x * yv[j].x) + 1.f), S0);  \
    S1 = fmaf(wwv[j].y,                                                                  \
              __builtin_amdgcn_rcpf(__builtin_amdgcn_exp2f(uv.y * yv[j].y) + 1.f), S1);  \
    S0 = fmaf(wwv[j].z,                                                                  \
              __builtin_amdgcn_rcpf(__builtin_amdgcn_exp2f(uv.z * yv[j].z) + 1.f), S0);  \
    S1 = fmaf(wwv[j].w,                                                                  \
              __builtin_amdgcn_rcpf(__builtin_amdgcn_exp2f(uv.w * yv[j].w) + 1.f), S1);  \
  } while (0)

#define DO_N(nn, A)                                                                      \
  do {                                                                                   \
    float s0 = 0.f, s1 = 0.f;                                                            \
    QUAD(nn, 0, s0, s1); QUAD(nn, 1, s0, s1); QUAD(nn, 2, s0, s1); QUAD(nn, 3, s0, s1);  \
    QUAD(nn, 4, s0, s1); QUAD(nn, 5, s0, s1); QUAD(nn, 6, s0, s1); QUAD(nn, 7, s0, s1);  \
    A = s0 + s1;                                                                         \
  } while (0)

  float a0, a1, a2, a3, a4, a5, a6, a7;
  DO_N(0, a0); DO_N(1, a1); DO_N(2, a2); DO_N(3, a3);
  DO_N(4, a4); DO_N(5, a5); DO_N(6, a6); DO_N(7, a7);
#undef DO_N
#undef QUAD

  // ---- cross-fc sum ----
  red[0][fc][lane] = a0; red[1][fc][lane] = a1;
  red[2][fc][lane] = a2; red[3][fc][lane] = a3;
  red[4][fc][lane] = a4; red[5][fc][lane] = a5;
  red[6][fc][lane] = a6; red[7][fc][lane] = a7;
  __syncthreads();

  float S = 0.f;
#pragma unroll
  for (int k = 0; k < 8; ++k) S += red[w][k][lane];

  // row-min partial (over this block's 64 m)
  float r = S;
#pragma unroll
  for (int s = 32; s; s >>= 1) r = fminf(r, __shfl_xor(r, s));
  if (lane == 0) rminp[((size_t)b * 4 + mg) * N_ + n0 + w] = r;

  // col-min partial (over this block's 8 n)
  sm[w][lane] = S;
  __syncthreads();
  if (w == 0) {
    float c = sm[0][lane];
#pragma unroll
    for (int k = 1; k < 8; ++k) c = fminf(c, sm[k][lane]);
    cminp[((size_t)b * 16 + ns) * M_ + m0 + lane] = c;
  }
}

// ---------------------------------------------------------------------------
// KB v2: finish on 64 blocks (b x task x f-quarter), 256 threads.
// Softmax weights recomputed per block (cheap); each block pools only its
// 64 f-columns -> 4x the latency-hiding of the 16-block version.
// Softmax inputs are -2 * min-partials (exact, shift-invariant).
// ---------------------------------------------------------------------------
__global__ __launch_bounds__(256) void kb_final(
    const float* __restrict__ x, const float* __restrict__ y,
    const float* __restrict__ rminp, const float* __restrict__ cminp,
    float* __restrict__ out) {
  const int b    = blockIdx.x;
  const int task = blockIdx.y;
  const int fq   = blockIdx.z;
  const int tid  = threadIdx.x;
  const int w    = tid >> 6;
  __shared__ float wgt[M_];
  __shared__ float redv[4];
  __shared__ float part[4][64];

  if (task == 0) {
    // softmax over n (128) of (-2 * min_m S)
    float rv = -INFINITY;
    if (tid < N_) {
      float v = INFINITY;
#pragma unroll
      for (int mg = 0; mg < 4; ++mg)
        v = fminf(v, rminp[((size_t)b * 4 + mg) * N_ + tid]);
      rv = -2.f * v;
    }
    float m1 = rv;
#pragma unroll
    for (int s = 32; s; s >>= 1) m1 = fmaxf(m1, __shfl_xor(m1, s));
    if ((tid & 63) == 0) redv[w] = m1;
    __syncthreads();
    m1 = fmaxf(fmaxf(redv[0], redv[1]), fmaxf(redv[2], redv[3]));
    __syncthreads();
    const float e1 = (tid < N_) ? __expf(rv - m1) : 0.f;
    float s1 = e1;
#pragma unroll
    for (int s = 32; s; s >>= 1) s1 += __shfl_xor(s1, s);
    if ((tid & 63) == 0) redv[w] = s1;
    __syncthreads();
    s1 = redv[0] + redv[1] + redv[2] + redv[3];
    if (tid < N_) wgt[tid] = e1 / s1;
    __syncthreads();

    const int f = fq * 64 + (tid & 63);
    const int q = w;   // 0..3
    float acc = 0.f;
#pragma unroll 8
    for (int n = q; n < N_; n += 4)
      acc = fmaf(wgt[n], x[(size_t)(b * N_ + n) * F_ + f], acc);
    part[q][tid & 63] = acc;
    __syncthreads();
    if (tid < 64)
      out[b * (2 * F_) + fq * 64 + tid] =
          part[0][tid] + part[1][tid] + part[2][tid] + part[3][tid];
  } else {
    // softmax over m (256) of (-2 * min_n S)
    float cv;
    {
      float c = INFINITY;
#pragma unroll
      for (int ns = 0; ns < 16; ++ns)
        c = fminf(c, cminp[((size_t)b * 16 + ns) * M_ + tid]);
      cv = -2.f * c;
    }
    float m2 = cv;
#pragma unroll
    for (int s = 32; s; s >>= 1) m2 = fmaxf(m2, __shfl_xor(m2, s));
    if ((tid & 63) == 0) redv[w] = m2;
    __syncthreads();
    m2 = fmaxf(fmaxf(redv[0], redv[1]), fmaxf(redv[2], redv[3]));
    __syncthreads();
    const float e2 = __expf(cv - m2);
    float s2 = e2;
#pragma unroll
    for (int s = 32; s; s >>= 1) s2 += __shfl_xor(s2, s);
    if ((tid & 63) == 0) redv[w] = s2;
    __syncthreads();
    s2 = redv[0] + redv[1] + redv[2] + redv[3];
    wgt[tid] = e2 / s2;
    __syncthreads();

    const int f = fq * 64 + (tid & 63);
    const int q = w;   // 0..3
    float acc = 0.f;
#pragma unroll 8
    for (int m = q; m < M_; m += 4)
      acc = fmaf(wgt[m], y[(size_t)(b * M_ + m) * F_ + f], acc);
    part[q][tid & 63] = acc;
    __syncthreads();
    if (tid < 64)
      out[b * (2 * F_) + F_ + fq * 64 + tid] =
          part[0][tid] + part[1][tid] + part[2][tid] + part[3][tid];
  }
}

// ---------------------------------------------------------------------------
extern "C" void kernel_launch(void* const* d_in, const int* in_sizes, int n_in,
                              void* d_out, int out_size, void* d_ws, size_t ws_size,
                              hipStream_t stream) {
  (void)in_sizes; (void)n_in; (void)out_size; (void)ws_size;
  const float* x  = (const float*)d_in[0];
  const float* y  = (const float*)d_in[1];
  const float* Uw = (const float*)d_in[2];
  const float* Ub = (const float*)d_in[3];
  const float* Ww = (const float*)d_in[4];
  // d_in[5] (W_b) unused: max/softmax pipeline is shift-invariant.

  float* u     = (float*)d_ws;                 // [B][N][F]    262144 f
  float* rminp = u + B_ * N_ * F_;             // [B][4][N]      4096 f
  float* cminp = rminp + B_ * 4 * N_;          // [B][16][M]   32768 f
  float* outp  = (float*)d_out;

  k1_lite<<<dim3((B_ * N_) / 4), 256, 0, stream>>>(x, Uw, Ub, u);
  k2_alpha<<<dim3(4, 16, B_), 512, 0, stream>>>(u, y, Ww, rminp, cminp);
  kb_final<<<dim3(B_, 2, 4), 256, 0, stream>>>(x, y, rminp, cminp, outp);
}